// Round 1
// baseline (901.070 us; speedup 1.0000x reference)
//
#include <hip/hip_runtime.h>
#include <hip/hip_bf16.h>

// ---------- types ----------
typedef __attribute__((ext_vector_type(8))) short short8;
typedef __attribute__((ext_vector_type(4))) float f32x4;

#define EMB 128
#define OUT 256
#define NRAD 6
#define NDENSE 3

static __device__ __forceinline__ unsigned short f32_to_bf16(float f) {
    union { float f; unsigned u; } v; v.f = f;
    unsigned r = v.u + 0x7fffu + ((v.u >> 16) & 1u);   // round-nearest-even
    return (unsigned short)(r >> 16);
}
static __device__ __forceinline__ float bf16_to_f32(unsigned short h) {
    union { unsigned u; float f; } v; v.u = ((unsigned)h) << 16;
    return v.f;
}

// ---------- CSR build ----------
__global__ void hist_kernel(const int* __restrict__ src, int* __restrict__ counts, int E) {
    int stride = gridDim.x * blockDim.x;
    for (int e = blockIdx.x * blockDim.x + threadIdx.x; e < E; e += stride)
        atomicAdd(&counts[src[e]], 1);
}

__global__ __launch_bounds__(1024) void scan_kernel(const int* __restrict__ counts,
                                                    int* __restrict__ offsets, int n) {
    __shared__ int sums[1024];
    int t = threadIdx.x;
    int chunk = (n + 1023) >> 10;
    int lo = t * chunk;
    int hi = lo + chunk; if (hi > n) hi = n;
    int s = 0;
    for (int i = lo; i < hi; ++i) s += counts[i];
    sums[t] = s;
    __syncthreads();
    for (int d = 1; d < 1024; d <<= 1) {
        int v = (t >= d) ? sums[t - d] : 0;
        __syncthreads();
        sums[t] += v;
        __syncthreads();
    }
    int base = (t == 0) ? 0 : sums[t - 1];
    for (int i = lo; i < hi; ++i) { offsets[i] = base; base += counts[i]; }
    if (t == 1023) offsets[n] = base;   // total == E
}

__global__ void scatter_kernel(const int* __restrict__ src, const int* __restrict__ offsets,
                               int* __restrict__ counts /*consumed to 0*/,
                               int* __restrict__ perm, int E) {
    int stride = gridDim.x * blockDim.x;
    for (int e = blockIdx.x * blockDim.x + threadIdx.x; e < E; e += stride) {
        int s = src[e];
        int idx = atomicSub(&counts[s], 1) - 1;   // unique slot within node
        perm[offsets[s] + idx] = e;
    }
}

// ---------- weight prep (f32 -> bf16) ----------
__global__ void prep_w_kernel(const float* __restrict__ Wup, const float* __restrict__ Wd,
                              unsigned short* __restrict__ out) {
    const int n1 = OUT * EMB;
    const int n2 = NDENSE * OUT * OUT;
    int stride = gridDim.x * blockDim.x;
    for (int i = blockIdx.x * blockDim.x + threadIdx.x; i < n1 + n2; i += stride)
        out[i] = f32_to_bf16(i < n1 ? Wup[i] : Wd[i - n1]);
}

// ---------- fused edge transform + per-node gather-sum ----------
// one block (128 threads) per node; thread f owns column f
__global__ __launch_bounds__(128) void edge_accum_kernel(
        const float* __restrict__ m, const float* __restrict__ rbf,
        const int* __restrict__ perm, const int* __restrict__ offsets,
        const float* __restrict__ W_rbf, unsigned short* __restrict__ t_bf) {
    int nidx = blockIdx.x;
    int f = threadIdx.x;
    // per-thread W_rbf row (6 floats)
    const float* wr = W_rbf + f * NRAD;
    float w0 = wr[0], w1 = wr[1], w2 = wr[2], w3 = wr[3], w4 = wr[4], w5 = wr[5];
    int beg = offsets[nidx], end = offsets[nidx + 1];
    float acc = 0.f;
    int i = beg;
    int e = (i < end) ? perm[i] : 0;
    for (; i < end; ++i) {
        int e_next = (i + 1 < end) ? perm[i + 1] : 0;
        const float* rb = rbf + (size_t)e * NRAD;
        float proj = w0 * rb[0] + w1 * rb[1] + w2 * rb[2]
                   + w3 * rb[3] + w4 * rb[4] + w5 * rb[5];
        acc += m[(size_t)e * EMB + f] * proj;
        e = e_next;
    }
    t_bf[(size_t)nidx * EMB + f] = f32_to_bf16(acc);
}

// ---------- bf16 MFMA GEMM: C[M,256] = act(A[M,K] @ Bw^T + bias) ----------
// A: [M,K] bf16.  Bw: [256,K] bf16 (row o = weights for output col o).
// block = 256 threads (4 waves); block tile = 64 rows x 256 cols;
// wave w -> rows [blk*64 + w*16, +16), all 256 cols (16 col-tiles).
template<int K, int ACT>
__global__ __launch_bounds__(256) void gemm_kernel(
        const unsigned short* __restrict__ A, const unsigned short* __restrict__ Bw,
        const float* __restrict__ bias, unsigned short* __restrict__ C, int M) {
    const int w    = threadIdx.x >> 6;
    const int lane = threadIdx.x & 63;
    const int r     = lane & 15;
    const int khalf = lane >> 4;          // 0..3
    const int row0  = blockIdx.x * 64 + w * 16;

    f32x4 acc[16];
#pragma unroll
    for (int i = 0; i < 16; ++i) acc[i] = (f32x4){0.f, 0.f, 0.f, 0.f};

    const int arow = row0 + r;
    const bool rowok = (arow < M);
    const unsigned short* Arow = A + (size_t)arow * K;

    for (int ks = 0; ks < K; ks += 32) {
        int ka = ks + khalf * 8;
        short8 afrag;
        if (rowok) afrag = *(const short8*)(Arow + ka);
        else       afrag = (short8){0,0,0,0,0,0,0,0};
#pragma unroll
        for (int ct = 0; ct < 16; ++ct) {
            int col = ct * 16 + r;
            short8 bfrag = *(const short8*)(Bw + (size_t)col * K + ka);
            acc[ct] = __builtin_amdgcn_mfma_f32_16x16x32_bf16(afrag, bfrag, acc[ct], 0, 0, 0);
        }
    }

    // epilogue: D layout col=lane&15, row=(lane>>4)*4+reg  [verified m89]
    const int orow_base = row0 + khalf * 4;
#pragma unroll
    for (int ct = 0; ct < 16; ++ct) {
        int col = ct * 16 + r;
        float b = bias ? bias[col] : 0.f;
#pragma unroll
        for (int reg = 0; reg < 4; ++reg) {
            int orow = orow_base + reg;
            if (orow < M) {
                float x = acc[ct][reg] + b;
                if (ACT) x = x / (1.f + __expf(-x));   // silu
                C[(size_t)orow * OUT + col] = f32_to_bf16(x);
            }
        }
    }
}

// ---------- per-graph sum (graph_ids sorted) ----------
__global__ __launch_bounds__(256) void reduce_kernel(
        const unsigned short* __restrict__ h, const int* __restrict__ gids,
        float* __restrict__ out, int M) {
    const int NODES_PER_BLOCK = 128;
    int c  = threadIdx.x;                 // column 0..255
    int n0 = blockIdx.x * NODES_PER_BLOCK;
    if (n0 >= M) return;
    int n1 = n0 + NODES_PER_BLOCK; if (n1 > M) n1 = M;
    float acc = 0.f;
    int cur = gids[n0];
    for (int n = n0; n < n1; ++n) {
        int g = gids[n];
        if (g != cur) { atomicAdd(&out[(size_t)cur * OUT + c], acc); acc = 0.f; cur = g; }
        acc += bf16_to_f32(h[(size_t)n * OUT + c]);
    }
    atomicAdd(&out[(size_t)cur * OUT + c], acc);
}

// ---------- host ----------
extern "C" void kernel_launch(void* const* d_in, const int* in_sizes, int n_in,
                              void* d_out, int out_size, void* d_ws, size_t ws_size,
                              hipStream_t stream) {
    const float* m         = (const float*)d_in[0];
    const float* rbf       = (const float*)d_in[1];
    const int*   src       = (const int*)d_in[2];
    const int*   gids      = (const int*)d_in[3];
    const float* W_rbf     = (const float*)d_in[4];
    const float* W_up      = (const float*)d_in[5];
    const float* W_dense   = (const float*)d_in[6];
    const float* b_dense   = (const float*)d_in[7];
    float* out = (float*)d_out;

    const int E = in_sizes[2];
    const int N = in_sizes[3];

    // workspace layout
    size_t off = 0;
    auto alloc = [&](size_t bytes) -> void* {
        void* p = (char*)d_ws + off;
        off += (bytes + 255) & ~(size_t)255;
        return p;
    };
    int* counts  = (int*)alloc((size_t)N * 4);
    int* offsets = (int*)alloc(((size_t)N + 1) * 4);
    int* perm    = (int*)alloc((size_t)E * 4);
    unsigned short* t_bf = (unsigned short*)alloc((size_t)N * EMB * 2);
    unsigned short* h0   = (unsigned short*)alloc((size_t)N * OUT * 2);
    unsigned short* h1   = (unsigned short*)alloc((size_t)N * OUT * 2);
    unsigned short* Wbf  = (unsigned short*)alloc((size_t)(OUT * EMB + NDENSE * OUT * OUT) * 2);
    unsigned short* Wup_bf = Wbf;
    unsigned short* Wd_bf  = Wbf + OUT * EMB;

    // zero what needs zeroing (harness poisons ws/out with 0xAA once)
    hipMemsetAsync(counts, 0, (size_t)N * 4, stream);
    hipMemsetAsync(out, 0, (size_t)out_size * 4, stream);

    // CSR build
    hist_kernel<<<1024, 256, 0, stream>>>(src, counts, E);
    scan_kernel<<<1, 1024, 0, stream>>>(counts, offsets, N);
    scatter_kernel<<<1024, 256, 0, stream>>>(src, offsets, counts, perm, E);

    // weights -> bf16
    prep_w_kernel<<<256, 256, 0, stream>>>(W_up, W_dense, Wbf);

    // edge transform + node gather
    edge_accum_kernel<<<N, 128, 0, stream>>>(m, rbf, perm, offsets, W_rbf, t_bf);

    // up-projection (no bias, no act), then 3 dense+silu layers
    int gblocks = (N + 63) / 64;
    gemm_kernel<EMB, 0><<<gblocks, 256, 0, stream>>>(t_bf, Wup_bf, nullptr, h0, N);
    gemm_kernel<OUT, 1><<<gblocks, 256, 0, stream>>>(h0, Wd_bf + 0 * OUT * OUT, b_dense + 0 * OUT, h1, N);
    gemm_kernel<OUT, 1><<<gblocks, 256, 0, stream>>>(h1, Wd_bf + 1 * OUT * OUT, b_dense + 1 * OUT, h0, N);
    gemm_kernel<OUT, 1><<<gblocks, 256, 0, stream>>>(h0, Wd_bf + 2 * OUT * OUT, b_dense + 2 * OUT, h1, N);

    // per-graph readout
    reduce_kernel<<<(N + 127) / 128, 256, 0, stream>>>(h1, gids, out, N);
}